// Round 3
// baseline (489.416 us; speedup 1.0000x reference)
//
#include <hip/hip_runtime.h>
#include <cstdint>

// DimeNet interaction block, MI355X/gfx950.  Round 8.
// Round-7 counters: post 161us with ALL pipes idle (Mfma 5.6%, VALU 29%,
// HBM 14%, occ 37%) -> latency/barrier-bound, not resource-bound.  Data-flow
// audit: every sIn row range in post is WAVE-PRIVATE (A-frag reads rows
// wave*16+l15, epilogue writes wave*16+q*4+r, h0 staging tid>>2 in the same
// 16-row slice).  The 14 per-block barriers synchronized nothing but sBias.
// Round-8: (1) post: zero barriers -- bias from global (L2), final stage
// stores h straight to out from registers; LDS 34.8->17.4 KB => 8 blk/CU.
// (2) edge: same audit -> sA/sO wave-private, keep only B1 (sRad/sWr/bias
// are genuinely shared), delete B2/B3/B4.  bilinear/prep unchanged.
//
// Dtypes: float tensors f32; indices int32; out f32.
// Internals: f16 MFMA operands, fp32 accumulate; agg accumulated in f16 via
// packed atomics (absmax 0.031 @ thr 0.165).

#define H 128
#define NB 8
#define NR 6
#define SBC 42
#define LDA 136    // f16 lane pad for row-major tiles (16B-aligned rows)
#define WFRAG 16384  // f16 elems per fragment-linear 128x128 weight

using f16x8 = __attribute__((ext_vector_type(8))) _Float16;
using f32x4 = __attribute__((ext_vector_type(4))) float;

__device__ __forceinline__ float silu_f(float v){
  return v / (1.f + __expf(-v));
}
__device__ __forceinline__ f16x8 pack8(float4 a, float4 b){
  f16x8 h;
  h[0]=(_Float16)a.x; h[1]=(_Float16)a.y; h[2]=(_Float16)a.z; h[3]=(_Float16)a.w;
  h[4]=(_Float16)b.x; h[5]=(_Float16)b.y; h[6]=(_Float16)b.z; h[7]=(_Float16)b.w;
  return h;
}
// async global->LDS DMA, 16B/lane; LDS dest = wave-uniform base + lane*16
__device__ __forceinline__ void lds_dma16(const void* g, void* l){
  __builtin_amdgcn_global_load_lds(
      (const __attribute__((address_space(1))) unsigned int*)g,
      (__attribute__((address_space(3))) unsigned int*)l, 16, 0, 0);
}
// packed f16 atomic add (2 cols / 4B)
__device__ __forceinline__ void atomic_pk_add_f16(_Float16* addr, float lo, float hi){
  union { _Float16 h[2]; unsigned u; } d;
  d.h[0] = (_Float16)lo; d.h[1] = (_Float16)hi;
  asm volatile("global_atomic_pk_add_f16 %0, %1, off"
               :: "v"(addr), "v"(d.u) : "memory");
}

// ---------------- prep: weights -> MFMA-B-fragment-linear f16 ----------------
// wf slots: 0=w_from 1=w_to 2=rb0 3=rb1 4=lin 5=ra00 6=ra01 7=ra10 8=ra11
// Mapping: wf[m][c*8+j] = (f16) w_m[(kk*32+q*8+j)*128 + nt*16+l15]
//   where c=(nt*4+kk)*64+l, q=l>>4, l15=l&15.
__global__ void prep_kernel(const float* __restrict__ w_from,
                            const float* __restrict__ w_to,
                            const float* __restrict__ rb_w,
                            const float* __restrict__ lin_w,
                            const float* __restrict__ ra_w,
                            const float* __restrict__ Wb,
                            _Float16* __restrict__ wf,
                            _Float16* __restrict__ Wf)
{
  int idx = blockIdx.x*256 + threadIdx.x;
  if (blockIdx.x < 72){                 // 72*256 == 9*2048 exactly
    int m = idx >> 11, c = idx & 2047;
    int nt = c >> 8, kk = (c>>6)&3, l = c&63, q = l>>4, l15 = l&15;
    const float* src;
    switch(m){
      case 0: src = w_from;       break;
      case 1: src = w_to;         break;
      case 2: src = rb_w;         break;
      case 3: src = rb_w + 16384; break;
      case 4: src = lin_w;        break;
      case 5: src = ra_w;         break;
      case 6: src = ra_w + 16384; break;
      case 7: src = ra_w + 32768; break;
      default: src = ra_w + 49152; break;
    }
    const float* p = src + (size_t)(kk*32 + q*8)*H + nt*16 + l15;
    f16x8 o;
    #pragma unroll
    for (int j=0;j<8;j++) o[j] = (_Float16)p[(size_t)j*H];
    *reinterpret_cast<f16x8*>(wf + (size_t)m*WFRAG + c*8) = o;
  } else {
    int t = idx - 72*256;               // < 16384 (64 blocks)
    int j = t >> 11, c = t & 2047;
    int nt = c >> 8, kk = (c>>6)&3, l = c&63, q = l>>4, l15 = l&15;
    const float4* p = reinterpret_cast<const float4*>(
        Wb + ((size_t)(nt*16+l15)*NB + j)*H + kk*32 + q*8);
    *reinterpret_cast<f16x8*>(Wf + (size_t)j*WFRAG + c*8) = pack8(p[0], p[1]);
  }
}

// ---------------- edge: x_kj -> d_out (f16), agg(init)=x_ji -> ws (f16) ----------------
// B-fragments from global (L2-resident frag-linear weights); sA/sO wave-private
// 16-row slices -> only one barrier (shared sRad/sWr/bias staging).
__global__ __launch_bounds__(256,3) void edge_kernel(
    const float* __restrict__ x,
    const float* __restrict__ radial,
    const float* __restrict__ w_rbf,
    const _Float16* __restrict__ wf,
    const float* __restrict__ b_from,
    const float* __restrict__ b_to,
    _Float16* __restrict__ x_kj, _Float16* __restrict__ agg, int E)
{
  __shared__ alignas(16) _Float16 sA[64*LDA];
  __shared__ alignas(16) _Float16 sO[64*LDA];
  __shared__ float sRad[64*8];
  __shared__ float sWr[128*8];
  __shared__ float sBf[128];
  __shared__ float sBt[128];
  int tid = threadIdx.x;
  int e0 = blockIdx.x*64;
  int wave = tid>>6, lane = tid&63, l15 = lane&15, q = lane>>4;

  { // stage x tile (f32 -> f16), zero OOB rows; rows tid>>2 are wave-private
    int row = tid>>2, cs = (tid&3)*32;
    bool ok = (e0+row) < E;
    const float4* src = reinterpret_cast<const float4*>(x + (size_t)(e0+row)*H + cs);
    #pragma unroll
    for (int i=0;i<4;i++){
      float4 u0{0,0,0,0}, u1{0,0,0,0};
      if (ok){ u0 = src[2*i]; u1 = src[2*i+1]; }
      *reinterpret_cast<f16x8*>(&sA[row*LDA + cs + i*8]) = pack8(u0,u1);
    }
  }
  for (int i=tid; i<64*NR; i+=256){
    int r=i/NR, c=i%NR;
    sRad[r*8+c] = (e0+r < E) ? radial[(size_t)(e0+r)*NR + c] : 0.f;
  }
  for (int i=tid; i<NR*H; i+=256){
    int c=i>>7, n=i&127;
    sWr[n*8+c] = w_rbf[i];
  }
  if (tid < H){ sBf[tid] = b_from[tid]; sBt[tid] = b_to[tid]; }
  __syncthreads();                   // B1: shared sRad/sWr/bias ready

  f32x4 acc[8];
  auto gemm = [&](const _Float16* wsl){
    #pragma unroll
    for (int nt=0;nt<8;nt++) acc[nt] = f32x4{0.f,0.f,0.f,0.f};
    int ar = (wave*16 + l15)*LDA;
    const _Float16* wl = wsl + (size_t)lane*8;
    #pragma unroll
    for (int kk=0;kk<4;kk++){
      f16x8 bfr[8];
      #pragma unroll
      for (int nt=0;nt<8;nt++)
        bfr[nt] = *reinterpret_cast<const f16x8*>(wl + (size_t)(nt*4+kk)*512);
      f16x8 a = *reinterpret_cast<const f16x8*>(&sA[ar + kk*32 + q*8]);
      #pragma unroll
      for (int nt=0;nt<8;nt++)
        acc[nt] = __builtin_amdgcn_mfma_f32_16x16x32_f16(a, bfr[nt], acc[nt], 0,0,0);
    }
  };

  gemm(wf);  // x @ w_from
  #pragma unroll
  for (int nt=0;nt<8;nt++)
    #pragma unroll
    for (int r=0;r<4;r++){
      int rl = wave*16 + q*4 + r, col = nt*16 + l15;
      float v = silu_f(acc[nt][r] + sBf[col]);
      float rb = 0.f;
      #pragma unroll
      for (int c=0;c<NR;c++) rb += sRad[rl*8+c]*sWr[col*8+c];
      sO[rl*LDA+col] = (_Float16)(v*rb);
    }
  // no barrier: sO slice is wave-private; in-wave lgkmcnt orders RAW
  { // coalesced f16 store x_kj -> d_out
    int row=tid>>2, cs=(tid&3)*32;
    if (e0+row < E)
      #pragma unroll
      for (int i=0;i<4;i++)
        *reinterpret_cast<f16x8*>(x_kj + (size_t)(e0+row)*H + cs + i*8) =
          *reinterpret_cast<const f16x8*>(&sO[row*LDA + cs + i*8]);
  }
  gemm(wf + WFRAG);  // x @ w_to
  #pragma unroll
  for (int nt=0;nt<8;nt++)
    #pragma unroll
    for (int r=0;r<4;r++){
      int rl = wave*16 + q*4 + r, col = nt*16 + l15;
      sO[rl*LDA+col] = (_Float16)silu_f(acc[nt][r] + sBt[col]);
    }
  { // agg init = x_ji, f16 store into ws
    int row=tid>>2, cs=(tid&3)*32;
    if (e0+row < E)
      #pragma unroll
      for (int i=0;i<4;i++)
        *reinterpret_cast<f16x8*>(agg + (size_t)(e0+row)*H + cs + i*8) =
          *reinterpret_cast<const f16x8*>(&sO[row*LDA + cs + i*8]);
  }
}

// ---------------- bilinear: reg A-frags + DMA W staging + pk-f16 atomics ----------------
__global__ __launch_bounds__(256,3) void bilinear_kernel(
    const _Float16* __restrict__ x_kj,
    const float* __restrict__ sph,
    const float* __restrict__ w_sbf,
    const _Float16* __restrict__ Wf,
    const int* __restrict__ e_from, const int* __restrict__ e_to,
    _Float16* __restrict__ agg)
{
  __shared__ alignas(16) _Float16 wch[WFRAG];   // 32 KB frag W chunk; f32 sph scratch pre-loop
  __shared__ float ssb[128*NB];
  __shared__ float sw[SBC*NB];
  __shared__ int sdst[128];
  int tid = threadIdx.x;
  long long t0 = (long long)blockIdx.x * 128;
  int wave = tid>>6, lane = tid&63, l15 = lane&15, q = lane>>4;
  int m0 = wave*32;

  // gather A-fragments straight to registers (reused across all 8 jj chunks)
  int ef0 = e_from[t0 + m0 + l15];
  int ef1 = e_from[t0 + m0 + 16 + l15];
  f16x8 aR0[4], aR1[4];
  #pragma unroll
  for (int kk=0;kk<4;kk++){
    aR0[kk] = *reinterpret_cast<const f16x8*>(x_kj + (size_t)ef0*H + kk*32 + q*8);
    aR1[kk] = *reinterpret_cast<const f16x8*>(x_kj + (size_t)ef1*H + kk*32 + q*8);
  }

  { // stage 128 spherical rows (f32) into wch scratch (21.5 KB <= 32 KB)
    float4* scr = reinterpret_cast<float4*>(wch);
    const float4* g = reinterpret_cast<const float4*>(sph + t0*SBC);
    for (int i=tid; i<128*SBC/4; i+=256) scr[i] = g[i];
  }
  for (int i=tid; i<SBC*NB; i+=256) sw[i] = w_sbf[i];
  if (tid < 128) sdst[tid] = e_to[t0 + tid];
  __syncthreads();
  { // inline sbf: row=tid>>1, cols half*4..half*4+3 (wave-self-contained rows)
    int row = tid>>1, half = tid&1;
    const float* srow = reinterpret_cast<const float*>(wch) + row*SBC;
    float a4[4] = {0.f,0.f,0.f,0.f};
    for (int c=0;c<SBC;c++){
      float v = srow[c];
      #pragma unroll
      for (int cc=0;cc<4;cc++) a4[cc] += v * sw[c*NB + half*4 + cc];
    }
    #pragma unroll
    for (int cc=0;cc<4;cc++) ssb[row*NB + half*4 + cc] = a4[cc];
  }

  f32x4 acc[2][8];
  #pragma unroll
  for (int mt=0;mt<2;mt++)
    #pragma unroll
    for (int nt=0;nt<8;nt++) acc[mt][nt] = f32x4{0.f,0.f,0.f,0.f};

  for (int jj=0;jj<NB;jj++){
    __syncthreads();   // wch free: iter0 sbf-scratch reads done; else prev MFMA reads
    { // DMA-stage W chunk jj: frag-linear == lane-linear, 8x 1KB per wave
      const _Float16* gs = Wf + (size_t)jj*WFRAG + (size_t)(wave*64 + lane)*8;
      _Float16* ls = wch + (size_t)(wave*64)*8;
      #pragma unroll
      for (int u=0;u<8;u++)
        lds_dma16(gs + (size_t)u*2048, ls + (size_t)u*2048);
    }
    __syncthreads();   // vmcnt(0) drained before barrier -> chunk visible
    _Float16 s0 = (_Float16)ssb[(m0+l15)*NB + jj];
    _Float16 s1 = (_Float16)ssb[(m0+16+l15)*NB + jj];
    #pragma unroll
    for (int kk=0;kk<4;kk++){
      f16x8 a0 = aR0[kk] * s0;     // A-fragment = sbf[w][jj] * gathered[w][l]
      f16x8 a1 = aR1[kk] * s1;
      #pragma unroll
      for (int nt=0;nt<8;nt++){
        f16x8 b = *reinterpret_cast<const f16x8*>(&wch[((nt*4+kk)*64 + lane)*8]);
        acc[0][nt] = __builtin_amdgcn_mfma_f32_16x16x32_f16(a0, b, acc[0][nt], 0,0,0);
        acc[1][nt] = __builtin_amdgcn_mfma_f32_16x16x32_f16(a1, b, acc[1][nt], 0,0,0);
      }
    }
  }

  // packed f16 atomic scatter: shfl-xor pairs 2 adjacent cols per lane; each
  // wave-op covers 4 full 64B lines (32 instrs/wave vs 64 f32 before).
  int odd = l15 & 1;
  #pragma unroll
  for (int mt=0;mt<2;mt++)
    #pragma unroll
    for (int ntp=0;ntp<4;ntp++)
      #pragma unroll
      for (int r=0;r<4;r++){
        float a = acc[mt][2*ntp  ][r];     // col 32*ntp      + l15
        float b = acc[mt][2*ntp+1][r];     // col 32*ntp + 16 + l15
        float ax = __shfl_xor(a, 1);
        float bx = __shfl_xor(b, 1);
        int rl  = m0 + mt*16 + q*4 + r;
        int col = 32*ntp + (odd ? 15 + l15 : l15);   // even 4B-aligned base
        atomic_pk_add_f16(agg + (size_t)sdst[rl]*H + col,
                          odd ? bx : a, odd ? b : ax);
      }
}

// ---------------- post: 64-row tiles, 7 GEMM stages, ZERO barriers ----------------
// All LDS traffic is wave-private 16-row slices; bias from global (L2); final
// stage stores h straight to out from registers.  LDS 17.4 KB -> 8 blk/CU.
__global__ __launch_bounds__(256,6) void post_kernel(
    const float* __restrict__ x, const _Float16* __restrict__ agg,
    const _Float16* __restrict__ wf,
    const float* __restrict__ rb_b, const float* __restrict__ lin_b,
    const float* __restrict__ ra_b,
    float* __restrict__ out, int E)
{
  __shared__ alignas(16) _Float16 sIn[64*LDA];   // 17408 B
  int tid = threadIdx.x, e0 = blockIdx.x*64;
  int wave = tid>>6, lane = tid&63, l15 = lane&15, q = lane>>4;

  const float* bptr[7] = {rb_b, rb_b+128, lin_b, ra_b, ra_b+128, ra_b+256, ra_b+384};

  { // h0 = agg (= x_ji + scattered msg), f16 load; rows tid>>2 wave-private
    int row=tid>>2, cs=(tid&3)*32;
    bool ok = (e0+row) < E;
    f16x8 z;
    #pragma unroll
    for (int j=0;j<8;j++) z[j] = (_Float16)0.f;
    #pragma unroll
    for (int i=0;i<4;i++){
      f16x8 v = z;
      if (ok) v = *reinterpret_cast<const f16x8*>(agg + (size_t)(e0+row)*H + cs + i*8);
      *reinterpret_cast<f16x8*>(&sIn[row*LDA + cs + i*8]) = v;
    }
  }
  // no barrier: in-wave lgkmcnt orders the wave-private RAW
  float h[8][4];   // C-layout: row=wave*16+q*4+r, col=nt*16+l15
  #pragma unroll
  for (int nt=0;nt<8;nt++)
    #pragma unroll
    for (int r=0;r<4;r++)
      h[nt][r] = (float)sIn[(wave*16+q*4+r)*LDA + nt*16 + l15];

  f32x4 acc[8];
  #pragma unroll
  for (int s=0;s<7;s++){
    #pragma unroll
    for (int nt=0;nt<8;nt++) acc[nt] = f32x4{0.f,0.f,0.f,0.f};
    float bcol[8];               // bias for this stage's 8 columns (L2 hit)
    #pragma unroll
    for (int nt=0;nt<8;nt++) bcol[nt] = bptr[s][nt*16 + l15];
    int ar = (wave*16 + l15)*LDA;
    const _Float16* wl = wf + (size_t)(s+2)*WFRAG + (size_t)lane*8;
    #pragma unroll
    for (int kk=0;kk<4;kk++){
      f16x8 bfr[8];
      #pragma unroll
      for (int nt=0;nt<8;nt++)
        bfr[nt] = *reinterpret_cast<const f16x8*>(wl + (size_t)(nt*4+kk)*512);
      f16x8 a = *reinterpret_cast<const f16x8*>(&sIn[ar + kk*32 + q*8]);
      #pragma unroll
      for (int nt=0;nt<8;nt++)
        acc[nt] = __builtin_amdgcn_mfma_f32_16x16x32_f16(a, bfr[nt], acc[nt], 0,0,0);
    }
    // epilogue writes the same wave-private rows; lgkmcnt orders vs next ds_read
    #pragma unroll
    for (int nt=0;nt<8;nt++)
      #pragma unroll
      for (int r=0;r<4;r++){
        int rl = wave*16 + q*4 + r, col = nt*16 + l15;
        float v = silu_f(acc[nt][r] + bcol[nt]);
        if (s==0 || s==3 || s==5){            // first half of residual MLP
          sIn[rl*LDA+col] = (_Float16)v;
        } else if (s==1 || s==4){             // close residual: h += v
          h[nt][r] += v;
          sIn[rl*LDA+col] = (_Float16)h[nt][r];
        } else if (s==2){                     // h = silu(..) + x
          bool ok = (e0+rl) < E;
          float xv = ok ? x[(size_t)(e0+rl)*H + col] : 0.f;
          h[nt][r] = v + xv;
          sIn[rl*LDA+col] = (_Float16)h[nt][r];
        } else {                              // s==6: final h += v -> direct store
          h[nt][r] += v;
          if ((e0+rl) < E) out[(size_t)(e0+rl)*H + col] = h[nt][r];
        }
      }
  }
}

extern "C" void kernel_launch(void* const* d_in, const int* in_sizes, int n_in,
                              void* d_out, int out_size, void* d_ws, size_t ws_size,
                              hipStream_t stream)
{
  const float* x      = (const float*)d_in[0];
  const float* radial = (const float*)d_in[1];
  const float* sph    = (const float*)d_in[2];
  const int* e_from   = (const int*)d_in[3];
  const int* e_to     = (const int*)d_in[4];
  const float* w_rbf  = (const float*)d_in[5];
  const float* w_sbf  = (const float*)d_in[6];
  const float* w_from = (const float*)d_in[7];
  const float* b_from = (const float*)d_in[8];
  const float* w_to   = (const float*)d_in[9];
  const float* b_to   = (const float*)d_in[10];
  const float* Wb     = (const float*)d_in[11];
  const float* rb_w   = (const float*)d_in[12];
  const float* rb_b   = (const float*)d_in[13];
  const float* lin_w  = (const float*)d_in[14];
  const float* lin_b  = (const float*)d_in[15];
  const float* ra_w   = (const float*)d_in[16];
  const float* ra_b   = (const float*)d_in[17];

  int E = in_sizes[0] / H;      // 100000
  int T = in_sizes[3];          // 262144

  // d_out: x_kj f16[E][H] (25.6 MB) during edge/bilinear; final out f32 [E][H].
  // ws: agg f16[E][H] (25.6 MB) + 9 frag weights (288 KB) + 8 frag W (256 KB).
  char* ws = (char*)d_ws;
  _Float16* aggh = (_Float16*)ws;
  _Float16* wf   = (_Float16*)(ws + (size_t)E*H*2);
  _Float16* Wf   = wf + 9*WFRAG;
  _Float16* x_kj = (_Float16*)d_out;

  prep_kernel<<<136, 256, 0, stream>>>(w_from, w_to, rb_w, lin_w, ra_w, Wb, wf, Wf);
  edge_kernel<<<(E+63)/64, 256, 0, stream>>>(x, radial, w_rbf, wf, b_from, b_to,
                                             x_kj, aggh, E);
  bilinear_kernel<<<T/128, 256, 0, stream>>>(x_kj, sph, w_sbf, Wf, e_from, e_to, aggh);
  post_kernel<<<(E+63)/64, 256, 0, stream>>>(x, aggh, wf, rb_b, lin_b, ra_b,
                                             (float*)d_out, E);
}

// Round 4
// 382.981 us; speedup vs baseline: 1.2779x; 1.2779x over previous
//
#include <hip/hip_runtime.h>
#include <cstdint>

// DimeNet interaction block, MI355X/gfx950.  Round 9.
// Round-8 post-mortem: (256,6) bound -> VGPR 40 -> h/acc spilled (FETCH+73MB,
// WRITE+96MB), post 161->206us.  Occupancy/barriers are NOT post's wall:
// ~160us floor across 3 structures.  Revised theory: per-WAVE global B-reads
// (each wave pulls the full 32KB weight matrix per stage = 1.4 GB through the
// L1/L2 return path, L1-thrashed by the agg/x/out streams) are the wall.
// Round-9: stage weights per-BLOCK via global_load_lds DMA (zero registers,
// proven in bilinear; frag-linear layout == DMA lane-linear dest).  4x less
// weight traffic, LDS-path delivery, no prefetch spills.  post: 49KB LDS,
// 3 blk/CU, 2 barriers/stage, h in regs, direct reg->out store.  edge: same
// DMA staging per gemm (w_to DMA hidden under epilogue1), 3 barriers.
//
// Dtypes: float tensors f32; indices int32; out f32.
// Internals: f16 MFMA operands, fp32 accumulate; agg accumulated in f16 via
// packed atomics (absmax 0.031 @ thr 0.165).

#define H 128
#define NB 8
#define NR 6
#define SBC 42
#define LDA 136    // f16 lane pad for row-major tiles (16B-aligned rows)
#define WFRAG 16384  // f16 elems per fragment-linear 128x128 weight

using f16x8 = __attribute__((ext_vector_type(8))) _Float16;
using f32x4 = __attribute__((ext_vector_type(4))) float;

__device__ __forceinline__ float silu_f(float v){
  return v / (1.f + __expf(-v));
}
__device__ __forceinline__ f16x8 pack8(float4 a, float4 b){
  f16x8 h;
  h[0]=(_Float16)a.x; h[1]=(_Float16)a.y; h[2]=(_Float16)a.z; h[3]=(_Float16)a.w;
  h[4]=(_Float16)b.x; h[5]=(_Float16)b.y; h[6]=(_Float16)b.z; h[7]=(_Float16)b.w;
  return h;
}
// async global->LDS DMA, 16B/lane; LDS dest = wave-uniform base + lane*16
__device__ __forceinline__ void lds_dma16(const void* g, void* l){
  __builtin_amdgcn_global_load_lds(
      (const __attribute__((address_space(1))) unsigned int*)g,
      (__attribute__((address_space(3))) unsigned int*)l, 16, 0, 0);
}
// packed f16 atomic add (2 cols / 4B)
__device__ __forceinline__ void atomic_pk_add_f16(_Float16* addr, float lo, float hi){
  union { _Float16 h[2]; unsigned u; } d;
  d.h[0] = (_Float16)lo; d.h[1] = (_Float16)hi;
  asm volatile("global_atomic_pk_add_f16 %0, %1, off"
               :: "v"(addr), "v"(d.u) : "memory");
}

// ---------------- prep: weights -> MFMA-B-fragment-linear f16 ----------------
// wf slots: 0=w_from 1=w_to 2=rb0 3=rb1 4=lin 5=ra00 6=ra01 7=ra10 8=ra11
// Mapping: wf[m][c*8+j] = (f16) w_m[(kk*32+q*8+j)*128 + nt*16+l15]
//   where c=(nt*4+kk)*64+l, q=l>>4, l15=l&15.
__global__ void prep_kernel(const float* __restrict__ w_from,
                            const float* __restrict__ w_to,
                            const float* __restrict__ rb_w,
                            const float* __restrict__ lin_w,
                            const float* __restrict__ ra_w,
                            const float* __restrict__ Wb,
                            _Float16* __restrict__ wf,
                            _Float16* __restrict__ Wf)
{
  int idx = blockIdx.x*256 + threadIdx.x;
  if (blockIdx.x < 72){                 // 72*256 == 9*2048 exactly
    int m = idx >> 11, c = idx & 2047;
    int nt = c >> 8, kk = (c>>6)&3, l = c&63, q = l>>4, l15 = l&15;
    const float* src;
    switch(m){
      case 0: src = w_from;       break;
      case 1: src = w_to;         break;
      case 2: src = rb_w;         break;
      case 3: src = rb_w + 16384; break;
      case 4: src = lin_w;        break;
      case 5: src = ra_w;         break;
      case 6: src = ra_w + 16384; break;
      case 7: src = ra_w + 32768; break;
      default: src = ra_w + 49152; break;
    }
    const float* p = src + (size_t)(kk*32 + q*8)*H + nt*16 + l15;
    f16x8 o;
    #pragma unroll
    for (int j=0;j<8;j++) o[j] = (_Float16)p[(size_t)j*H];
    *reinterpret_cast<f16x8*>(wf + (size_t)m*WFRAG + c*8) = o;
  } else {
    int t = idx - 72*256;               // < 16384 (64 blocks)
    int j = t >> 11, c = t & 2047;
    int nt = c >> 8, kk = (c>>6)&3, l = c&63, q = l>>4, l15 = l&15;
    const float4* p = reinterpret_cast<const float4*>(
        Wb + ((size_t)(nt*16+l15)*NB + j)*H + kk*32 + q*8);
    *reinterpret_cast<f16x8*>(Wf + (size_t)j*WFRAG + c*8) = pack8(p[0], p[1]);
  }
}

// ---------------- edge: x_kj -> d_out (f16), agg(init)=x_ji -> ws (f16) ----------------
// Weights DMA-staged per block per gemm (32 KB, zero registers); 3 barriers.
__global__ __launch_bounds__(256,2) void edge_kernel(
    const float* __restrict__ x,
    const float* __restrict__ radial,
    const float* __restrict__ w_rbf,
    const _Float16* __restrict__ wf,
    const float* __restrict__ b_from,
    const float* __restrict__ b_to,
    _Float16* __restrict__ x_kj, _Float16* __restrict__ agg, int E)
{
  __shared__ alignas(16) _Float16 sA[64*LDA];
  __shared__ alignas(16) _Float16 sO[64*LDA];
  __shared__ alignas(16) _Float16 sW[WFRAG];
  __shared__ float sRad[64*8];
  __shared__ float sWr[128*8];
  __shared__ float sBf[128];
  __shared__ float sBt[128];
  int tid = threadIdx.x;
  int e0 = blockIdx.x*64;
  int wave = tid>>6, lane = tid&63, l15 = lane&15, q = lane>>4;

  { // DMA w_from -> sW (in flight across the whole staging phase)
    const _Float16* gs = wf + (size_t)(wave*64 + lane)*8;
    _Float16* ls = sW + (size_t)wave*512;
    #pragma unroll
    for (int u=0;u<8;u++) lds_dma16(gs + (size_t)u*2048, ls + (size_t)u*2048);
  }
  { // stage x tile (f32 -> f16), zero OOB rows; rows tid>>2 are wave-private
    int row = tid>>2, cs = (tid&3)*32;
    bool ok = (e0+row) < E;
    const float4* src = reinterpret_cast<const float4*>(x + (size_t)(e0+row)*H + cs);
    #pragma unroll
    for (int i=0;i<4;i++){
      float4 u0{0,0,0,0}, u1{0,0,0,0};
      if (ok){ u0 = src[2*i]; u1 = src[2*i+1]; }
      *reinterpret_cast<f16x8*>(&sA[row*LDA + cs + i*8]) = pack8(u0,u1);
    }
  }
  for (int i=tid; i<64*NR; i+=256){
    int r=i/NR, c=i%NR;
    sRad[r*8+c] = (e0+r < E) ? radial[(size_t)(e0+r)*NR + c] : 0.f;
  }
  for (int i=tid; i<NR*H; i+=256){
    int c=i>>7, n=i&127;
    sWr[n*8+c] = w_rbf[i];
  }
  if (tid < H){ sBf[tid] = b_from[tid]; sBt[tid] = b_to[tid]; }
  __syncthreads();                   // B1: staging + DMA drained (vmcnt0@barrier)

  f32x4 acc[8];
  auto gemm = [&](){
    #pragma unroll
    for (int nt=0;nt<8;nt++) acc[nt] = f32x4{0.f,0.f,0.f,0.f};
    int ar = (wave*16 + l15)*LDA;
    #pragma unroll
    for (int kk=0;kk<4;kk++){
      f16x8 a = *reinterpret_cast<const f16x8*>(&sA[ar + kk*32 + q*8]);
      #pragma unroll
      for (int nt=0;nt<8;nt++){
        f16x8 b = *reinterpret_cast<const f16x8*>(&sW[((nt*4+kk)*64 + lane)*8]);
        acc[nt] = __builtin_amdgcn_mfma_f32_16x16x32_f16(a, b, acc[nt], 0,0,0);
      }
    }
  };

  gemm();                            // x @ w_from
  __syncthreads();                   // B2: sW reads done by all waves
  { // DMA w_to -> sW; latency hides under epilogue1 below
    const _Float16* gs = wf + WFRAG + (size_t)(wave*64 + lane)*8;
    _Float16* ls = sW + (size_t)wave*512;
    #pragma unroll
    for (int u=0;u<8;u++) lds_dma16(gs + (size_t)u*2048, ls + (size_t)u*2048);
  }
  #pragma unroll
  for (int nt=0;nt<8;nt++)
    #pragma unroll
    for (int r=0;r<4;r++){
      int rl = wave*16 + q*4 + r, col = nt*16 + l15;
      float v = silu_f(acc[nt][r] + sBf[col]);
      float rb = 0.f;
      #pragma unroll
      for (int c=0;c<NR;c++) rb += sRad[rl*8+c]*sWr[col*8+c];
      sO[rl*LDA+col] = (_Float16)(v*rb);
    }
  { // coalesced f16 store x_kj -> d_out (sO rows wave-private, in-wave RAW)
    int row=tid>>2, cs=(tid&3)*32;
    if (e0+row < E)
      #pragma unroll
      for (int i=0;i<4;i++)
        *reinterpret_cast<f16x8*>(x_kj + (size_t)(e0+row)*H + cs + i*8) =
          *reinterpret_cast<const f16x8*>(&sO[row*LDA + cs + i*8]);
  }
  __syncthreads();                   // B3: w_to DMA drained
  gemm();                            // x @ w_to
  #pragma unroll
  for (int nt=0;nt<8;nt++)
    #pragma unroll
    for (int r=0;r<4;r++){
      int rl = wave*16 + q*4 + r, col = nt*16 + l15;
      sO[rl*LDA+col] = (_Float16)silu_f(acc[nt][r] + sBt[col]);
    }
  { // agg init = x_ji, f16 store into ws (wave-private rows)
    int row=tid>>2, cs=(tid&3)*32;
    if (e0+row < E)
      #pragma unroll
      for (int i=0;i<4;i++)
        *reinterpret_cast<f16x8*>(agg + (size_t)(e0+row)*H + cs + i*8) =
          *reinterpret_cast<const f16x8*>(&sO[row*LDA + cs + i*8]);
  }
}

// ---------------- bilinear: reg A-frags + DMA W staging + pk-f16 atomics ----------------
__global__ __launch_bounds__(256,3) void bilinear_kernel(
    const _Float16* __restrict__ x_kj,
    const float* __restrict__ sph,
    const float* __restrict__ w_sbf,
    const _Float16* __restrict__ Wf,
    const int* __restrict__ e_from, const int* __restrict__ e_to,
    _Float16* __restrict__ agg)
{
  __shared__ alignas(16) _Float16 wch[WFRAG];   // 32 KB frag W chunk; f32 sph scratch pre-loop
  __shared__ float ssb[128*NB];
  __shared__ float sw[SBC*NB];
  __shared__ int sdst[128];
  int tid = threadIdx.x;
  long long t0 = (long long)blockIdx.x * 128;
  int wave = tid>>6, lane = tid&63, l15 = lane&15, q = lane>>4;
  int m0 = wave*32;

  // gather A-fragments straight to registers (reused across all 8 jj chunks)
  int ef0 = e_from[t0 + m0 + l15];
  int ef1 = e_from[t0 + m0 + 16 + l15];
  f16x8 aR0[4], aR1[4];
  #pragma unroll
  for (int kk=0;kk<4;kk++){
    aR0[kk] = *reinterpret_cast<const f16x8*>(x_kj + (size_t)ef0*H + kk*32 + q*8);
    aR1[kk] = *reinterpret_cast<const f16x8*>(x_kj + (size_t)ef1*H + kk*32 + q*8);
  }

  { // stage 128 spherical rows (f32) into wch scratch (21.5 KB <= 32 KB)
    float4* scr = reinterpret_cast<float4*>(wch);
    const float4* g = reinterpret_cast<const float4*>(sph + t0*SBC);
    for (int i=tid; i<128*SBC/4; i+=256) scr[i] = g[i];
  }
  for (int i=tid; i<SBC*NB; i+=256) sw[i] = w_sbf[i];
  if (tid < 128) sdst[tid] = e_to[t0 + tid];
  __syncthreads();
  { // inline sbf: row=tid>>1, cols half*4..half*4+3 (wave-self-contained rows)
    int row = tid>>1, half = tid&1;
    const float* srow = reinterpret_cast<const float*>(wch) + row*SBC;
    float a4[4] = {0.f,0.f,0.f,0.f};
    for (int c=0;c<SBC;c++){
      float v = srow[c];
      #pragma unroll
      for (int cc=0;cc<4;cc++) a4[cc] += v * sw[c*NB + half*4 + cc];
    }
    #pragma unroll
    for (int cc=0;cc<4;cc++) ssb[row*NB + half*4 + cc] = a4[cc];
  }

  f32x4 acc[2][8];
  #pragma unroll
  for (int mt=0;mt<2;mt++)
    #pragma unroll
    for (int nt=0;nt<8;nt++) acc[mt][nt] = f32x4{0.f,0.f,0.f,0.f};

  for (int jj=0;jj<NB;jj++){
    __syncthreads();   // wch free: iter0 sbf-scratch reads done; else prev MFMA reads
    { // DMA-stage W chunk jj: frag-linear == lane-linear, 8x 1KB per wave
      const _Float16* gs = Wf + (size_t)jj*WFRAG + (size_t)(wave*64 + lane)*8;
      _Float16* ls = wch + (size_t)(wave*64)*8;
      #pragma unroll
      for (int u=0;u<8;u++)
        lds_dma16(gs + (size_t)u*2048, ls + (size_t)u*2048);
    }
    __syncthreads();   // vmcnt(0) drained before barrier -> chunk visible
    _Float16 s0 = (_Float16)ssb[(m0+l15)*NB + jj];
    _Float16 s1 = (_Float16)ssb[(m0+16+l15)*NB + jj];
    #pragma unroll
    for (int kk=0;kk<4;kk++){
      f16x8 a0 = aR0[kk] * s0;     // A-fragment = sbf[w][jj] * gathered[w][l]
      f16x8 a1 = aR1[kk] * s1;
      #pragma unroll
      for (int nt=0;nt<8;nt++){
        f16x8 b = *reinterpret_cast<const f16x8*>(&wch[((nt*4+kk)*64 + lane)*8]);
        acc[0][nt] = __builtin_amdgcn_mfma_f32_16x16x32_f16(a0, b, acc[0][nt], 0,0,0);
        acc[1][nt] = __builtin_amdgcn_mfma_f32_16x16x32_f16(a1, b, acc[1][nt], 0,0,0);
      }
    }
  }

  // packed f16 atomic scatter: shfl-xor pairs 2 adjacent cols per lane; each
  // wave-op covers 4 full 64B lines (32 instrs/wave vs 64 f32 before).
  int odd = l15 & 1;
  #pragma unroll
  for (int mt=0;mt<2;mt++)
    #pragma unroll
    for (int ntp=0;ntp<4;ntp++)
      #pragma unroll
      for (int r=0;r<4;r++){
        float a = acc[mt][2*ntp  ][r];     // col 32*ntp      + l15
        float b = acc[mt][2*ntp+1][r];     // col 32*ntp + 16 + l15
        float ax = __shfl_xor(a, 1);
        float bx = __shfl_xor(b, 1);
        int rl  = m0 + mt*16 + q*4 + r;
        int col = 32*ntp + (odd ? 15 + l15 : l15);   // even 4B-aligned base
        atomic_pk_add_f16(agg + (size_t)sdst[rl]*H + col,
                          odd ? bx : a, odd ? b : ax);
      }
}

// ---------------- post: 64-row tiles, 7 GEMM stages, DMA-staged weights ----------------
// sW DMA'd once per block per stage (not per wave); h in regs; bias from L2;
// final stage stores straight to out.  LDS 49 KB -> 3 blk/CU.
__global__ __launch_bounds__(256,3) void post_kernel(
    const float* __restrict__ x, const _Float16* __restrict__ agg,
    const _Float16* __restrict__ wf,
    const float* __restrict__ rb_b, const float* __restrict__ lin_b,
    const float* __restrict__ ra_b,
    float* __restrict__ out, int E)
{
  __shared__ alignas(16) _Float16 sIn[64*LDA];   // 17408 B
  __shared__ alignas(16) _Float16 sW[WFRAG];     // 32768 B
  int tid = threadIdx.x, e0 = blockIdx.x*64;
  int wave = tid>>6, lane = tid&63, l15 = lane&15, q = lane>>4;

  const float* bptr[7] = {rb_b, rb_b+128, lin_b, ra_b, ra_b+128, ra_b+256, ra_b+384};

  { // h0 = agg (= x_ji + scattered msg), f16 load; rows tid>>2 wave-private
    int row=tid>>2, cs=(tid&3)*32;
    bool ok = (e0+row) < E;
    f16x8 z;
    #pragma unroll
    for (int j=0;j<8;j++) z[j] = (_Float16)0.f;
    #pragma unroll
    for (int i=0;i<4;i++){
      f16x8 v = z;
      if (ok) v = *reinterpret_cast<const f16x8*>(agg + (size_t)(e0+row)*H + cs + i*8);
      *reinterpret_cast<f16x8*>(&sIn[row*LDA + cs + i*8]) = v;
    }
  }
  // in-wave lgkmcnt orders the wave-private RAW on sIn
  float h[8][4];   // C-layout: row=wave*16+q*4+r, col=nt*16+l15
  #pragma unroll
  for (int nt=0;nt<8;nt++)
    #pragma unroll
    for (int r=0;r<4;r++)
      h[nt][r] = (float)sIn[(wave*16+q*4+r)*LDA + nt*16 + l15];

  f32x4 acc[8];
  #pragma unroll
  for (int s=0;s<7;s++){
    if (s > 0) __syncthreads();      // A: prev stage's sW reads done
    { // DMA stage-s weights -> sW (32 KB per block, zero registers)
      const _Float16* gs = wf + (size_t)(s+2)*WFRAG + (size_t)(wave*64 + lane)*8;
      _Float16* ls = sW + (size_t)wave*512;
      #pragma unroll
      for (int u=0;u<8;u++) lds_dma16(gs + (size_t)u*2048, ls + (size_t)u*2048);
    }
    float bcol[8];                   // stage bias, L2-hit scalar loads
    #pragma unroll
    for (int nt=0;nt<8;nt++) bcol[nt] = bptr[s][nt*16 + l15];
    #pragma unroll
    for (int nt=0;nt<8;nt++) acc[nt] = f32x4{0.f,0.f,0.f,0.f};
    __syncthreads();                 // B: DMA drained (vmcnt0@barrier)
    int ar = (wave*16 + l15)*LDA;
    #pragma unroll
    for (int kk=0;kk<4;kk++){
      f16x8 a = *reinterpret_cast<const f16x8*>(&sIn[ar + kk*32 + q*8]);
      #pragma unroll
      for (int nt=0;nt<8;nt++){
        f16x8 b = *reinterpret_cast<const f16x8*>(&sW[((nt*4+kk)*64 + lane)*8]);
        acc[nt] = __builtin_amdgcn_mfma_f32_16x16x32_f16(a, b, acc[nt], 0,0,0);
      }
    }
    // epilogue writes wave-private sIn rows; in-wave lgkmcnt orders vs next read
    #pragma unroll
    for (int nt=0;nt<8;nt++)
      #pragma unroll
      for (int r=0;r<4;r++){
        int rl = wave*16 + q*4 + r, col = nt*16 + l15;
        float v = silu_f(acc[nt][r] + bcol[nt]);
        if (s==0 || s==3 || s==5){            // first half of residual MLP
          sIn[rl*LDA+col] = (_Float16)v;
        } else if (s==1 || s==4){             // close residual: h += v
          h[nt][r] += v;
          sIn[rl*LDA+col] = (_Float16)h[nt][r];
        } else if (s==2){                     // h = silu(..) + x
          bool ok = (e0+rl) < E;
          float xv = ok ? x[(size_t)(e0+rl)*H + col] : 0.f;
          h[nt][r] = v + xv;
          sIn[rl*LDA+col] = (_Float16)h[nt][r];
        } else {                              // s==6: final h += v -> direct store
          h[nt][r] += v;
          if ((e0+rl) < E) out[(size_t)(e0+rl)*H + col] = h[nt][r];
        }
      }
  }
}

extern "C" void kernel_launch(void* const* d_in, const int* in_sizes, int n_in,
                              void* d_out, int out_size, void* d_ws, size_t ws_size,
                              hipStream_t stream)
{
  const float* x      = (const float*)d_in[0];
  const float* radial = (const float*)d_in[1];
  const float* sph    = (const float*)d_in[2];
  const int* e_from   = (const int*)d_in[3];
  const int* e_to     = (const int*)d_in[4];
  const float* w_rbf  = (const float*)d_in[5];
  const float* w_sbf  = (const float*)d_in[6];
  const float* w_from = (const float*)d_in[7];
  const float* b_from = (const float*)d_in[8];
  const float* w_to   = (const float*)d_in[9];
  const float* b_to   = (const float*)d_in[10];
  const float* Wb     = (const float*)d_in[11];
  const float* rb_w   = (const float*)d_in[12];
  const float* rb_b   = (const float*)d_in[13];
  const float* lin_w  = (const float*)d_in[14];
  const float* lin_b  = (const float*)d_in[15];
  const float* ra_w   = (const float*)d_in[16];
  const float* ra_b   = (const float*)d_in[17];

  int E = in_sizes[0] / H;      // 100000
  int T = in_sizes[3];          // 262144

  // d_out: x_kj f16[E][H] (25.6 MB) during edge/bilinear; final out f32 [E][H].
  // ws: agg f16[E][H] (25.6 MB) + 9 frag weights (288 KB) + 8 frag W (256 KB).
  char* ws = (char*)d_ws;
  _Float16* aggh = (_Float16*)ws;
  _Float16* wf   = (_Float16*)(ws + (size_t)E*H*2);
  _Float16* Wf   = wf + 9*WFRAG;
  _Float16* x_kj = (_Float16*)d_out;

  prep_kernel<<<136, 256, 0, stream>>>(w_from, w_to, rb_w, lin_w, ra_w, Wb, wf, Wf);
  edge_kernel<<<(E+63)/64, 256, 0, stream>>>(x, radial, w_rbf, wf, b_from, b_to,
                                             x_kj, aggh, E);
  bilinear_kernel<<<T/128, 256, 0, stream>>>(x_kj, sph, w_sbf, Wf, e_from, e_to, aggh);
  post_kernel<<<(E+63)/64, 256, 0, stream>>>(x, aggh, wf, rb_b, lin_b, ra_b,
                                             (float*)d_out, E);
}